// Round 1
// baseline (2645.386 us; speedup 1.0000x reference)
//
#include <hip/hip_runtime.h>
#include <hip/hip_bf16.h>

#define S_LEN 2048
#define EMB 1024
#define NH 16
#define HD 64
// M = B*S = 4096 rows

// ---------------------------------------------------------------------------
// Kernel 1: proj = x @ qkv_w^T  (M=4096, N=3072, K=1024), epilogue applies
// cos(acc)*cos(qp[n&63]) and scatters to Q/K/V bf16 in [B,H,S,D] layout.
// ---------------------------------------------------------------------------
__global__ __launch_bounds__(256) void gemm_qkv(
    const float* __restrict__ x,   // [4096][1024]
    const float* __restrict__ w,   // [3072][1024]
    const float* __restrict__ qp,  // [64]
    __hip_bfloat16* __restrict__ Q,
    __hip_bfloat16* __restrict__ K,
    __hip_bfloat16* __restrict__ V)
{
    const int Kdim = 1024;
    __shared__ float As[16][65];
    __shared__ float Bs[16][65];
    const int m0 = blockIdx.y * 64;
    const int n0 = blockIdx.x * 64;
    const int t  = threadIdx.x;
    const int tx = t & 15, ty = t >> 4;

    float acc[4][4] = {};
    for (int k0 = 0; k0 < Kdim; k0 += 16) {
#pragma unroll
        for (int i = 0; i < 4; i++) {
            int idx = t * 4 + i;              // 0..1023, k fast
            int kk = idx & 15, mm = idx >> 4;
            As[kk][mm] = x[(long)(m0 + mm) * Kdim + k0 + kk];
        }
#pragma unroll
        for (int i = 0; i < 4; i++) {
            int idx = t * 4 + i;
            int kk = idx & 15, nn = idx >> 4;
            Bs[kk][nn] = w[(long)(n0 + nn) * Kdim + k0 + kk];
        }
        __syncthreads();
#pragma unroll
        for (int kk = 0; kk < 16; kk++) {
            float a[4], b[4];
#pragma unroll
            for (int i = 0; i < 4; i++) a[i] = As[kk][ty * 4 + i];
#pragma unroll
            for (int j = 0; j < 4; j++) b[j] = Bs[kk][tx * 4 + j];
#pragma unroll
            for (int i = 0; i < 4; i++)
#pragma unroll
                for (int j = 0; j < 4; j++) acc[i][j] += a[i] * b[j];
        }
        __syncthreads();
    }
    // epilogue: quantum activation + scatter
#pragma unroll
    for (int i = 0; i < 4; i++) {
        int m = m0 + ty * 4 + i;
        int b = m >> 11, s = m & 2047;
#pragma unroll
        for (int j = 0; j < 4; j++) {
            int n = n0 + tx * 4 + j;
            int d = n & 63;
            float val = __cosf(acc[i][j]) * __cosf(qp[d]);
            int which = n >> 10;
            int e = n & 1023;
            int h = e >> 6;
            long idx = ((long)(b * NH + h) * S_LEN + s) * HD + d;
            __hip_bfloat16 bv = __float2bfloat16(val);
            if (which == 0)      Q[idx] = bv;
            else if (which == 1) K[idx] = bv;
            else                 V[idx] = bv;
        }
    }
}

// ---------------------------------------------------------------------------
// Kernel 2: flash attention per (b,h). Q tile = 32 rows, K/V tiles = 64 rows.
// 256 threads: thread t -> q-row g = t>>3, d-columns (t&7)*8 .. +7.
// Writes O in [B,S,H*D] (= [B,S,E]) bf16 layout.
// ---------------------------------------------------------------------------
__global__ __launch_bounds__(256) void attn_kernel(
    const __hip_bfloat16* __restrict__ Q,
    const __hip_bfloat16* __restrict__ K,
    const __hip_bfloat16* __restrict__ V,
    __hip_bfloat16* __restrict__ O)
{
    __shared__ float Qs[32][65];
    __shared__ float Ks[64][65];
    __shared__ float Vs[64][65];
    __shared__ float Ps[32][65];

    const int bh = blockIdx.y;          // 0..31
    const int b  = bh >> 4, h = bh & 15;
    const int q0 = blockIdx.x * 32;
    const int t  = threadIdx.x;
    const int g  = t >> 3;              // q row within tile (0..31)
    const int u  = t & 7;               // d-column group (0..7)

    const __hip_bfloat16* Qb = Q + ((long)bh * S_LEN + q0) * HD;
    const __hip_bfloat16* Kb = K + (long)bh * S_LEN * HD;
    const __hip_bfloat16* Vb = V + (long)bh * S_LEN * HD;

    for (int i = t; i < 32 * 64; i += 256) {
        int r = i >> 6, d = i & 63;
        Qs[r][d] = __bfloat162float(Qb[r * 64 + d]) * 0.125f;  // fold 1/sqrt(64)
    }
    __syncthreads();

    float m_i = -1e30f, l_i = 0.f;
    float o[8] = {};

    for (int kt = 0; kt < S_LEN; kt += 64) {
        for (int i = t; i < 64 * 64; i += 256) {
            int r = i >> 6, d = i & 63;
            Ks[r][d] = __bfloat162float(Kb[(long)(kt + r) * 64 + d]);
            Vs[r][d] = __bfloat162float(Vb[(long)(kt + r) * 64 + d]);
        }
        __syncthreads();

        float sc[8];
#pragma unroll
        for (int j = 0; j < 8; j++) {
            int key = u * 8 + j;
            float s = 0.f;
#pragma unroll
            for (int d = 0; d < 64; d++) s += Qs[g][d] * Ks[key][d];
            sc[j] = s;
        }
        float mx = sc[0];
#pragma unroll
        for (int j = 1; j < 8; j++) mx = fmaxf(mx, sc[j]);
#pragma unroll
        for (int off = 1; off < 8; off <<= 1) mx = fmaxf(mx, __shfl_xor(mx, off, 64));
        float m_new = fmaxf(m_i, mx);

        float p[8], ls = 0.f;
#pragma unroll
        for (int j = 0; j < 8; j++) { p[j] = __expf(sc[j] - m_new); ls += p[j]; }
#pragma unroll
        for (int off = 1; off < 8; off <<= 1) ls += __shfl_xor(ls, off, 64);

        float scale = __expf(m_i - m_new);
        l_i = l_i * scale + ls;
        m_i = m_new;
#pragma unroll
        for (int j = 0; j < 8; j++) Ps[g][u * 8 + j] = p[j];
#pragma unroll
        for (int j = 0; j < 8; j++) o[j] *= scale;
        __syncthreads();

#pragma unroll
        for (int key = 0; key < 64; key++) {
            float pv = Ps[g][key];
#pragma unroll
            for (int j = 0; j < 8; j++) o[j] += pv * Vs[key][u * 8 + j];
        }
        __syncthreads();
    }

    float inv = 1.f / l_i;
    long obase = ((long)b * S_LEN + q0 + g) * EMB + h * HD + u * 8;
#pragma unroll
    for (int j = 0; j < 8; j++) O[obase + j] = __float2bfloat16(o[j] * inv);
}

// ---------------------------------------------------------------------------
// Kernel 3: out = O @ out_w^T  (M=4096, N=1024, K=1024), O is bf16, out fp32.
// ---------------------------------------------------------------------------
__global__ __launch_bounds__(256) void gemm_out(
    const __hip_bfloat16* __restrict__ A,  // [4096][1024] bf16
    const float* __restrict__ w,           // [1024][1024]
    float* __restrict__ C)                 // [4096][1024]
{
    const int Kdim = 1024;
    __shared__ float As[16][65];
    __shared__ float Bs[16][65];
    const int m0 = blockIdx.y * 64;
    const int n0 = blockIdx.x * 64;
    const int t  = threadIdx.x;
    const int tx = t & 15, ty = t >> 4;

    float acc[4][4] = {};
    for (int k0 = 0; k0 < Kdim; k0 += 16) {
#pragma unroll
        for (int i = 0; i < 4; i++) {
            int idx = t * 4 + i;
            int kk = idx & 15, mm = idx >> 4;
            As[kk][mm] = __bfloat162float(A[(long)(m0 + mm) * Kdim + k0 + kk]);
        }
#pragma unroll
        for (int i = 0; i < 4; i++) {
            int idx = t * 4 + i;
            int kk = idx & 15, nn = idx >> 4;
            Bs[kk][nn] = w[(long)(n0 + nn) * Kdim + k0 + kk];
        }
        __syncthreads();
#pragma unroll
        for (int kk = 0; kk < 16; kk++) {
            float a[4], bb[4];
#pragma unroll
            for (int i = 0; i < 4; i++) a[i] = As[kk][ty * 4 + i];
#pragma unroll
            for (int j = 0; j < 4; j++) bb[j] = Bs[kk][tx * 4 + j];
#pragma unroll
            for (int i = 0; i < 4; i++)
#pragma unroll
                for (int j = 0; j < 4; j++) acc[i][j] += a[i] * bb[j];
        }
        __syncthreads();
    }
#pragma unroll
    for (int i = 0; i < 4; i++) {
        int m = m0 + ty * 4 + i;
#pragma unroll
        for (int j = 0; j < 4; j++) {
            int n = n0 + tx * 4 + j;
            C[(long)m * 1024 + n] = acc[i][j];
        }
    }
}

extern "C" void kernel_launch(void* const* d_in, const int* in_sizes, int n_in,
                              void* d_out, int out_size, void* d_ws, size_t ws_size,
                              hipStream_t stream) {
    const float* x     = (const float*)d_in[0];   // [2,2048,1024]
    const float* qkv_w = (const float*)d_in[1];   // [3072,1024]
    const float* out_w = (const float*)d_in[2];   // [1024,1024]
    const float* qp    = (const float*)d_in[3];   // [64]
    float* out = (float*)d_out;                   // [2,2048,1024] fp32

    const long NELEM = (long)2 * S_LEN * EMB;     // 4,194,304
    __hip_bfloat16* Q = (__hip_bfloat16*)d_ws;
    __hip_bfloat16* K = Q + NELEM;
    __hip_bfloat16* V = K + NELEM;
    __hip_bfloat16* O = V + NELEM;                // [B,S,E] bf16

    dim3 blk(256);
    gemm_qkv<<<dim3(3072 / 64, 4096 / 64), blk, 0, stream>>>(x, qkv_w, qp, Q, K, V);
    attn_kernel<<<dim3(S_LEN / 32, 32), blk, 0, stream>>>(Q, K, V, O);
    gemm_out<<<dim3(1024 / 64, 4096 / 64), blk, 0, stream>>>(O, out_w, out);
}

// Round 2
// 757.922 us; speedup vs baseline: 3.4903x; 3.4903x over previous
//
#include <hip/hip_runtime.h>
#include <hip/hip_bf16.h>

#define S_LEN 2048
#define EMB 1024
#define NH 16
#define HD 64
// M = B*S = 4096 rows

typedef __attribute__((ext_vector_type(8))) __bf16 bf16x8;
typedef __attribute__((ext_vector_type(4))) float f32x4;

// ---------------------------------------------------------------------------
// Kernel 1: proj = x @ qkv_w^T  (M=4096, N=3072, K=1024), epilogue applies
// cos(acc)*cos(qp[n&63]) and scatters to bf16:
//   Q -> [B,H,S,D] pre-scaled by 1/sqrt(D)=0.125
//   K -> [B,H,S,D]
//   V -> [B,H,D,S]  (transposed so attention's PV B-operand reads contiguous)
// ---------------------------------------------------------------------------
__global__ __launch_bounds__(256) void gemm_qkv(
    const float* __restrict__ x,   // [4096][1024]
    const float* __restrict__ w,   // [3072][1024]
    const float* __restrict__ qp,  // [64]
    __hip_bfloat16* __restrict__ Q,
    __hip_bfloat16* __restrict__ K,
    __hip_bfloat16* __restrict__ V)
{
    const int Kdim = 1024;
    __shared__ float As[16][65];
    __shared__ float Bs[16][65];
    const int m0 = blockIdx.y * 64;
    const int n0 = blockIdx.x * 64;
    const int t  = threadIdx.x;
    const int tx = t & 15, ty = t >> 4;

    float acc[4][4] = {};
    for (int k0 = 0; k0 < Kdim; k0 += 16) {
#pragma unroll
        for (int i = 0; i < 4; i++) {
            int idx = t * 4 + i;              // 0..1023, k fast
            int kk = idx & 15, mm = idx >> 4;
            As[kk][mm] = x[(long)(m0 + mm) * Kdim + k0 + kk];
        }
#pragma unroll
        for (int i = 0; i < 4; i++) {
            int idx = t * 4 + i;
            int kk = idx & 15, nn = idx >> 4;
            Bs[kk][nn] = w[(long)(n0 + nn) * Kdim + k0 + kk];
        }
        __syncthreads();
#pragma unroll
        for (int kk = 0; kk < 16; kk++) {
            float a[4], b[4];
#pragma unroll
            for (int i = 0; i < 4; i++) a[i] = As[kk][ty * 4 + i];
#pragma unroll
            for (int j = 0; j < 4; j++) b[j] = Bs[kk][tx * 4 + j];
#pragma unroll
            for (int i = 0; i < 4; i++)
#pragma unroll
                for (int j = 0; j < 4; j++) acc[i][j] += a[i] * b[j];
        }
        __syncthreads();
    }
    // epilogue: quantum activation + scatter
#pragma unroll
    for (int i = 0; i < 4; i++) {
        int m = m0 + ty * 4 + i;
        int b = m >> 11, s = m & 2047;
#pragma unroll
        for (int j = 0; j < 4; j++) {
            int n = n0 + tx * 4 + j;
            int d = n & 63;
            float val = __cosf(acc[i][j]) * __cosf(qp[d]);
            int which = n >> 10;
            int e = n & 1023;
            int h = e >> 6;
            int bh = b * NH + h;
            if (which == 0) {
                Q[((long)bh * S_LEN + s) * HD + d] = __float2bfloat16(val * 0.125f);
            } else if (which == 1) {
                K[((long)bh * S_LEN + s) * HD + d] = __float2bfloat16(val);
            } else {
                V[((long)bh * HD + d) * S_LEN + s] = __float2bfloat16(val);
            }
        }
    }
}

// ---------------------------------------------------------------------------
// Kernel 2: MFMA flash attention. Block = 4 waves, QBLK=64 (16 q-rows/wave),
// KVBLK=64. K and V^T tiles staged in XOR-swizzled LDS (row-major [64][128B],
// byte ^= (row&7)<<4 — G4 fix for the 32-way conflict). P staged per-wave in
// swizzled LDS (no cross-wave barrier needed). Scores scale pre-folded into Q.
// Writes O in [B,S,E] bf16.
// ---------------------------------------------------------------------------
__global__ __launch_bounds__(256) void attn_mfma(
    const __hip_bfloat16* __restrict__ Q,
    const __hip_bfloat16* __restrict__ K,
    const __hip_bfloat16* __restrict__ Vt,  // [B,H,D,S]
    __hip_bfloat16* __restrict__ O)
{
    __shared__ __align__(16) char Ksh[64 * 128];
    __shared__ __align__(16) char Vsh[64 * 128];
    __shared__ __align__(16) char Psh[4 * 16 * 128];

    const int bh = blockIdx.y;          // 0..31
    const int b  = bh >> 4, h = bh & 15;
    const int q0 = blockIdx.x * 64;
    const int t  = threadIdx.x;
    const int w  = t >> 6;              // wave 0..3
    const int l  = t & 63;              // lane
    const int lg = l >> 4;              // lane group 0..3
    const int lm = l & 15;

    // A-operand Q fragments: lane holds Q[q0+w*16+lm][lg*8 + i (+32)]
    const __hip_bfloat16* Qr =
        Q + ((long)bh * S_LEN + q0 + w * 16 + lm) * HD + lg * 8;
    const bf16x8 qa0 = *(const bf16x8*)(Qr);
    const bf16x8 qa1 = *(const bf16x8*)(Qr + 32);

    f32x4 oacc[4];
#pragma unroll
    for (int n = 0; n < 4; n++) oacc[n] = (f32x4){0.f, 0.f, 0.f, 0.f};
    float m_i[4] = {-1e30f, -1e30f, -1e30f, -1e30f};
    float l_i[4] = {0.f, 0.f, 0.f, 0.f};

    char* Pw = Psh + w * 2048;
    const char* Kgb = (const char*)(K + (long)bh * S_LEN * HD);
    const __hip_bfloat16* Vgb = Vt + (long)bh * HD * S_LEN;

    for (int kt = 0; kt < S_LEN; kt += 64) {
        __syncthreads();  // previous tile's LDS reads done
        // stage K tile [64 keys][64 d] and V^T tile [64 d][64 keys]
#pragma unroll
        for (int c = t; c < 512; c += 256) {
            int r = c >> 3, cb = (c & 7) * 16;
            int sw = r * 128 + (cb ^ ((r & 7) << 4));
            uint4 kv = *(const uint4*)(Kgb + ((long)(kt + r)) * 128 + cb);
            *(uint4*)(Ksh + sw) = kv;
            uint4 vv = *(const uint4*)((const char*)(Vgb + (long)r * S_LEN + kt) + cb);
            *(uint4*)(Vsh + sw) = vv;
        }
        __syncthreads();

        // ---- S = Q K^T (scale pre-folded into Q) ----
        f32x4 sacc[4];
#pragma unroll
        for (int n0 = 0; n0 < 4; n0++) {
            f32x4 s = (f32x4){0.f, 0.f, 0.f, 0.f};
            int row = n0 * 16 + lm;
            int swr = (row & 7) << 4;
            bf16x8 b0 = *(const bf16x8*)(Ksh + row * 128 + ((lg * 16) ^ swr));
            bf16x8 b1 = *(const bf16x8*)(Ksh + row * 128 + ((64 + lg * 16) ^ swr));
            s = __builtin_amdgcn_mfma_f32_16x16x32_bf16(qa0, b0, s, 0, 0, 0);
            s = __builtin_amdgcn_mfma_f32_16x16x32_bf16(qa1, b1, s, 0, 0, 0);
            sacc[n0] = s;
        }

        // ---- online softmax (row q = lg*4+r lives across 16 lanes) ----
#pragma unroll
        for (int r = 0; r < 4; r++) {
            float mx = fmaxf(fmaxf(sacc[0][r], sacc[1][r]),
                             fmaxf(sacc[2][r], sacc[3][r]));
            mx = fmaxf(mx, __shfl_xor(mx, 1, 64));
            mx = fmaxf(mx, __shfl_xor(mx, 2, 64));
            mx = fmaxf(mx, __shfl_xor(mx, 4, 64));
            mx = fmaxf(mx, __shfl_xor(mx, 8, 64));
            float mn = fmaxf(m_i[r], mx);
            float sc = __expf(m_i[r] - mn);
            m_i[r] = mn;
            int q = lg * 4 + r;
            int swp = (q & 7) << 4;
            float ls = 0.f;
#pragma unroll
            for (int n0 = 0; n0 < 4; n0++) {
                float p = __expf(sacc[n0][r] - mn);
                ls += p;
                int key = n0 * 16 + lm;
                *(__hip_bfloat16*)(Pw + q * 128 + ((key * 2) ^ swp)) =
                    __float2bfloat16(p);
            }
            ls += __shfl_xor(ls, 1, 64);
            ls += __shfl_xor(ls, 2, 64);
            ls += __shfl_xor(ls, 4, 64);
            ls += __shfl_xor(ls, 8, 64);
            l_i[r] = l_i[r] * sc + ls;
#pragma unroll
            for (int n0 = 0; n0 < 4; n0++) oacc[n0][r] *= sc;
        }

        // ---- O += P V  (A = P from per-wave LDS, B = V^T tile) ----
#pragma unroll
        for (int kk = 0; kk < 2; kk++) {
            bf16x8 pa = *(const bf16x8*)(
                Pw + lm * 128 + ((kk * 64 + lg * 16) ^ ((lm & 7) << 4)));
#pragma unroll
            for (int n0 = 0; n0 < 4; n0++) {
                int row = n0 * 16 + lm;  // d index
                bf16x8 vb = *(const bf16x8*)(
                    Vsh + row * 128 + ((kk * 64 + lg * 16) ^ ((row & 7) << 4)));
                oacc[n0] =
                    __builtin_amdgcn_mfma_f32_16x16x32_bf16(pa, vb, oacc[n0], 0, 0, 0);
            }
        }
    }

    // ---- normalize + write O [B,S,E] ----
#pragma unroll
    for (int r = 0; r < 4; r++) {
        float inv = 1.f / l_i[r];
        int qrow = q0 + w * 16 + lg * 4 + r;
        long base = ((long)b * S_LEN + qrow) * EMB + h * HD;
#pragma unroll
        for (int n0 = 0; n0 < 4; n0++)
            O[base + n0 * 16 + lm] = __float2bfloat16(oacc[n0][r] * inv);
    }
}

// ---------------------------------------------------------------------------
// Kernel 3: out = O @ out_w^T  (M=4096, N=1024, K=1024), O is bf16, out fp32.
// ---------------------------------------------------------------------------
__global__ __launch_bounds__(256) void gemm_out(
    const __hip_bfloat16* __restrict__ A,  // [4096][1024] bf16
    const float* __restrict__ w,           // [1024][1024]
    float* __restrict__ C)                 // [4096][1024]
{
    const int Kdim = 1024;
    __shared__ float As[16][65];
    __shared__ float Bs[16][65];
    const int m0 = blockIdx.y * 64;
    const int n0 = blockIdx.x * 64;
    const int t  = threadIdx.x;
    const int tx = t & 15, ty = t >> 4;

    float acc[4][4] = {};
    for (int k0 = 0; k0 < Kdim; k0 += 16) {
#pragma unroll
        for (int i = 0; i < 4; i++) {
            int idx = t * 4 + i;
            int kk = idx & 15, mm = idx >> 4;
            As[kk][mm] = __bfloat162float(A[(long)(m0 + mm) * Kdim + k0 + kk]);
        }
#pragma unroll
        for (int i = 0; i < 4; i++) {
            int idx = t * 4 + i;
            int kk = idx & 15, nn = idx >> 4;
            Bs[kk][nn] = w[(long)(n0 + nn) * Kdim + k0 + kk];
        }
        __syncthreads();
#pragma unroll
        for (int kk = 0; kk < 16; kk++) {
            float a[4], bb[4];
#pragma unroll
            for (int i = 0; i < 4; i++) a[i] = As[kk][ty * 4 + i];
#pragma unroll
            for (int j = 0; j < 4; j++) bb[j] = Bs[kk][tx * 4 + j];
#pragma unroll
            for (int i = 0; i < 4; i++)
#pragma unroll
                for (int j = 0; j < 4; j++) acc[i][j] += a[i] * bb[j];
        }
        __syncthreads();
    }
#pragma unroll
    for (int i = 0; i < 4; i++) {
        int m = m0 + ty * 4 + i;
#pragma unroll
        for (int j = 0; j < 4; j++) {
            int n = n0 + tx * 4 + j;
            C[(long)m * 1024 + n] = acc[i][j];
        }
    }
}

extern "C" void kernel_launch(void* const* d_in, const int* in_sizes, int n_in,
                              void* d_out, int out_size, void* d_ws, size_t ws_size,
                              hipStream_t stream) {
    const float* x     = (const float*)d_in[0];   // [2,2048,1024]
    const float* qkv_w = (const float*)d_in[1];   // [3072,1024]
    const float* out_w = (const float*)d_in[2];   // [1024,1024]
    const float* qp    = (const float*)d_in[3];   // [64]
    float* out = (float*)d_out;                   // [2,2048,1024] fp32

    const long NELEM = (long)2 * S_LEN * EMB;     // 4,194,304
    __hip_bfloat16* Q  = (__hip_bfloat16*)d_ws;   // [B,H,S,D] (×0.125)
    __hip_bfloat16* K  = Q + NELEM;               // [B,H,S,D]
    __hip_bfloat16* Vt = K + NELEM;               // [B,H,D,S]
    __hip_bfloat16* O  = Vt + NELEM;              // [B,S,E]

    dim3 blk(256);
    gemm_qkv<<<dim3(3072 / 64, 4096 / 64), blk, 0, stream>>>(x, qkv_w, qp, Q, K, Vt);
    attn_mfma<<<dim3(S_LEN / 64, 32), blk, 0, stream>>>(Q, K, Vt, O);
    gemm_out<<<dim3(1024 / 64, 4096 / 64), blk, 0, stream>>>(O, out_w, out);
}

// Round 3
// 197.855 us; speedup vs baseline: 13.3703x; 3.8307x over previous
//
#include <hip/hip_runtime.h>
#include <hip/hip_bf16.h>

#define S_LEN 2048
#define EMB 1024
#define NH 16
#define HD 64
// M = B*S = 4096 rows

typedef __attribute__((ext_vector_type(8))) __bf16 bf16x8;
typedef __attribute__((ext_vector_type(4))) float f32x4;

__device__ inline void gload_lds16(const void* g, void* l) {
    __builtin_amdgcn_global_load_lds(
        (const __attribute__((address_space(1))) unsigned int*)g,
        (__attribute__((address_space(3))) unsigned int*)l, 16, 0, 0);
}

// ---------------------------------------------------------------------------
// Kernel 0: fp32 -> bf16 conversion (vectorized, grid-stride)
// ---------------------------------------------------------------------------
__global__ __launch_bounds__(256) void cvt_f32_bf16(
    const float* __restrict__ in, __hip_bfloat16* __restrict__ out, long n)
{
    long i0 = ((long)blockIdx.x * 256 + threadIdx.x) * 4;
    long stride = (long)gridDim.x * 256 * 4;
    for (long i = i0; i < n; i += stride) {
        float4 v = *(const float4*)(in + i);
        __hip_bfloat16 b0 = __float2bfloat16(v.x);
        __hip_bfloat16 b1 = __float2bfloat16(v.y);
        __hip_bfloat16 b2 = __float2bfloat16(v.z);
        __hip_bfloat16 b3 = __float2bfloat16(v.w);
        ushort4 o = {*(unsigned short*)&b0, *(unsigned short*)&b1,
                     *(unsigned short*)&b2, *(unsigned short*)&b3};
        *(ushort4*)(out + i) = o;
    }
}

// ---------------------------------------------------------------------------
// MFMA GEMM core (m97 structure): C = A @ B^T, A [M][1024] bf16, B [N][1024]
// bf16. 128x128 tile, BK=64, 4 waves (2x2), 4x4 16x16 fragments per wave.
// global_load_lds w/ pre-swizzled source -> XOR-swizzled LDS (row&7)<<4.
// EPI=0: quantum epilogue (cos*cos, scatter Q/K/Vt).  EPI=1: fp32 C store.
// ---------------------------------------------------------------------------
template <int EPI>
__global__ __launch_bounds__(256) void gemm_mfma(
    const __hip_bfloat16* __restrict__ A,   // [M][1024]
    const __hip_bfloat16* __restrict__ B,   // [N][1024]
    const float* __restrict__ qp,           // [64] (EPI=0)
    __hip_bfloat16* __restrict__ Q,         // EPI=0 outputs
    __hip_bfloat16* __restrict__ Kp,
    __hip_bfloat16* __restrict__ Vt,
    float* __restrict__ C)                  // EPI=1 output
{
    const int Kd = 1024;
    __shared__ __align__(16) char Ash[128 * 128];  // 128 rows x 64 bf16
    __shared__ __align__(16) char Bsh[128 * 128];

    const int t  = threadIdx.x;
    const int w  = t >> 6;
    const int l  = t & 63;
    const int lg = l >> 4, lm = l & 15;
    const int wr = w >> 1, wc = w & 1;
    const int m0 = blockIdx.y * 128;
    const int n0 = blockIdx.x * 128;

    // staging: lane -> row r8 = l>>3 within 8-row chunk, 16B col (l&7),
    // source byte pre-swizzled so LDS[row][b] = G[row][b ^ ((row&7)<<4)]
    const int r8 = l >> 3;
    const int sb = ((l & 7) * 16) ^ (r8 << 4);
    const char* srcA = (const char*)A + ((long)(m0 + w * 32 + r8) * Kd) * 2 + sb;
    const char* srcB = (const char*)B + ((long)(n0 + w * 32 + r8) * Kd) * 2 + sb;

    f32x4 acc[4][4];
#pragma unroll
    for (int i = 0; i < 4; i++)
#pragma unroll
        for (int j = 0; j < 4; j++) acc[i][j] = (f32x4){0.f, 0.f, 0.f, 0.f};

    for (int kt = 0; kt < Kd * 2; kt += 128) {  // kt in bytes per row
#pragma unroll
        for (int j = 0; j < 4; j++) {
            gload_lds16(srcA + (long)j * 8 * Kd * 2 + kt, Ash + (w * 32 + j * 8) * 128);
            gload_lds16(srcB + (long)j * 8 * Kd * 2 + kt, Bsh + (w * 32 + j * 8) * 128);
        }
        __syncthreads();  // vmcnt(0) drain + all waves staged
#pragma unroll
        for (int kk = 0; kk < 2; kk++) {
            bf16x8 af[4], bfr[4];
            const int sw = (lm & 7) << 4;
            const int co = (kk * 64 + lg * 16);
#pragma unroll
            for (int mi = 0; mi < 4; mi++)
                af[mi] = *(const bf16x8*)(Ash + (wr * 64 + mi * 16 + lm) * 128 + (co ^ sw));
#pragma unroll
            for (int ni = 0; ni < 4; ni++)
                bfr[ni] = *(const bf16x8*)(Bsh + (wc * 64 + ni * 16 + lm) * 128 + (co ^ sw));
#pragma unroll
            for (int mi = 0; mi < 4; mi++)
#pragma unroll
                for (int ni = 0; ni < 4; ni++)
                    acc[mi][ni] = __builtin_amdgcn_mfma_f32_16x16x32_bf16(
                        af[mi], bfr[ni], acc[mi][ni], 0, 0, 0);
        }
        __syncthreads();  // compute done before restage
    }

    if constexpr (EPI == 0) {
        // quantum activation + scatter. which is block-uniform (BN=128 | 1024)
        const int which = n0 >> 10;
        float cqp[4];
#pragma unroll
        for (int ni = 0; ni < 4; ni++)
            cqp[ni] = __cosf(qp[(wc * 64 + ni * 16 + lm) & 63]);
#pragma unroll
        for (int mi = 0; mi < 4; mi++) {
#pragma unroll
            for (int r = 0; r < 4; r++) {
                int m = m0 + wr * 64 + mi * 16 + lg * 4 + r;
                int b = m >> 11, s = m & 2047;
#pragma unroll
                for (int ni = 0; ni < 4; ni++) {
                    int n = n0 + wc * 64 + ni * 16 + lm;
                    int d = n & 63;
                    int h = (n & 1023) >> 6;
                    int bh = b * NH + h;
                    float val = __cosf(acc[mi][ni][r]) * cqp[ni];
                    if (which == 0)
                        Q[((long)bh * S_LEN + s) * HD + d] = __float2bfloat16(val * 0.125f);
                    else if (which == 1)
                        Kp[((long)bh * S_LEN + s) * HD + d] = __float2bfloat16(val);
                    else
                        Vt[((long)bh * HD + d) * S_LEN + s] = __float2bfloat16(val);
                }
            }
        }
    } else {
#pragma unroll
        for (int mi = 0; mi < 4; mi++)
#pragma unroll
            for (int r = 0; r < 4; r++) {
                int m = m0 + wr * 64 + mi * 16 + lg * 4 + r;
#pragma unroll
                for (int ni = 0; ni < 4; ni++) {
                    int n = n0 + wc * 64 + ni * 16 + lm;
                    C[(long)m * 1024 + n] = acc[mi][ni][r];
                }
            }
    }
}

// ---------------------------------------------------------------------------
// Kernel 2: MFMA flash attention (unchanged from round 2).
// ---------------------------------------------------------------------------
__global__ __launch_bounds__(256) void attn_mfma(
    const __hip_bfloat16* __restrict__ Q,
    const __hip_bfloat16* __restrict__ K,
    const __hip_bfloat16* __restrict__ Vt,  // [B,H,D,S]
    __hip_bfloat16* __restrict__ O)
{
    __shared__ __align__(16) char Ksh[64 * 128];
    __shared__ __align__(16) char Vsh[64 * 128];
    __shared__ __align__(16) char Psh[4 * 16 * 128];

    const int bh = blockIdx.y;
    const int b  = bh >> 4, h = bh & 15;
    const int q0 = blockIdx.x * 64;
    const int t  = threadIdx.x;
    const int w  = t >> 6;
    const int l  = t & 63;
    const int lg = l >> 4;
    const int lm = l & 15;

    const __hip_bfloat16* Qr =
        Q + ((long)bh * S_LEN + q0 + w * 16 + lm) * HD + lg * 8;
    const bf16x8 qa0 = *(const bf16x8*)(Qr);
    const bf16x8 qa1 = *(const bf16x8*)(Qr + 32);

    f32x4 oacc[4];
#pragma unroll
    for (int n = 0; n < 4; n++) oacc[n] = (f32x4){0.f, 0.f, 0.f, 0.f};
    float m_i[4] = {-1e30f, -1e30f, -1e30f, -1e30f};
    float l_i[4] = {0.f, 0.f, 0.f, 0.f};

    char* Pw = Psh + w * 2048;
    const char* Kgb = (const char*)(K + (long)bh * S_LEN * HD);
    const __hip_bfloat16* Vgb = Vt + (long)bh * HD * S_LEN;

    for (int kt = 0; kt < S_LEN; kt += 64) {
        __syncthreads();
#pragma unroll
        for (int c = t; c < 512; c += 256) {
            int r = c >> 3, cb = (c & 7) * 16;
            int sw = r * 128 + (cb ^ ((r & 7) << 4));
            uint4 kv = *(const uint4*)(Kgb + ((long)(kt + r)) * 128 + cb);
            *(uint4*)(Ksh + sw) = kv;
            uint4 vv = *(const uint4*)((const char*)(Vgb + (long)r * S_LEN + kt) + cb);
            *(uint4*)(Vsh + sw) = vv;
        }
        __syncthreads();

        f32x4 sacc[4];
#pragma unroll
        for (int n0 = 0; n0 < 4; n0++) {
            f32x4 s = (f32x4){0.f, 0.f, 0.f, 0.f};
            int row = n0 * 16 + lm;
            int swr = (row & 7) << 4;
            bf16x8 b0 = *(const bf16x8*)(Ksh + row * 128 + ((lg * 16) ^ swr));
            bf16x8 b1 = *(const bf16x8*)(Ksh + row * 128 + ((64 + lg * 16) ^ swr));
            s = __builtin_amdgcn_mfma_f32_16x16x32_bf16(qa0, b0, s, 0, 0, 0);
            s = __builtin_amdgcn_mfma_f32_16x16x32_bf16(qa1, b1, s, 0, 0, 0);
            sacc[n0] = s;
        }

#pragma unroll
        for (int r = 0; r < 4; r++) {
            float mx = fmaxf(fmaxf(sacc[0][r], sacc[1][r]),
                             fmaxf(sacc[2][r], sacc[3][r]));
            mx = fmaxf(mx, __shfl_xor(mx, 1, 64));
            mx = fmaxf(mx, __shfl_xor(mx, 2, 64));
            mx = fmaxf(mx, __shfl_xor(mx, 4, 64));
            mx = fmaxf(mx, __shfl_xor(mx, 8, 64));
            float mn = fmaxf(m_i[r], mx);
            float sc = __expf(m_i[r] - mn);
            m_i[r] = mn;
            int q = lg * 4 + r;
            int swp = (q & 7) << 4;
            float ls = 0.f;
#pragma unroll
            for (int n0 = 0; n0 < 4; n0++) {
                float p = __expf(sacc[n0][r] - mn);
                ls += p;
                int key = n0 * 16 + lm;
                *(__hip_bfloat16*)(Pw + q * 128 + ((key * 2) ^ swp)) =
                    __float2bfloat16(p);
            }
            ls += __shfl_xor(ls, 1, 64);
            ls += __shfl_xor(ls, 2, 64);
            ls += __shfl_xor(ls, 4, 64);
            ls += __shfl_xor(ls, 8, 64);
            l_i[r] = l_i[r] * sc + ls;
#pragma unroll
            for (int n0 = 0; n0 < 4; n0++) oacc[n0][r] *= sc;
        }

#pragma unroll
        for (int kk = 0; kk < 2; kk++) {
            bf16x8 pa = *(const bf16x8*)(
                Pw + lm * 128 + ((kk * 64 + lg * 16) ^ ((lm & 7) << 4)));
#pragma unroll
            for (int n0 = 0; n0 < 4; n0++) {
                int row = n0 * 16 + lm;
                bf16x8 vb = *(const bf16x8*)(
                    Vsh + row * 128 + ((kk * 64 + lg * 16) ^ ((row & 7) << 4)));
                oacc[n0] =
                    __builtin_amdgcn_mfma_f32_16x16x32_bf16(pa, vb, oacc[n0], 0, 0, 0);
            }
        }
    }

#pragma unroll
    for (int r = 0; r < 4; r++) {
        float inv = 1.f / l_i[r];
        int qrow = q0 + w * 16 + lg * 4 + r;
        long base = ((long)b * S_LEN + qrow) * EMB + h * HD;
#pragma unroll
        for (int n0 = 0; n0 < 4; n0++)
            O[base + n0 * 16 + lm] = __float2bfloat16(oacc[n0][r] * inv);
    }
}

extern "C" void kernel_launch(void* const* d_in, const int* in_sizes, int n_in,
                              void* d_out, int out_size, void* d_ws, size_t ws_size,
                              hipStream_t stream) {
    const float* x     = (const float*)d_in[0];   // [2,2048,1024]
    const float* qkv_w = (const float*)d_in[1];   // [3072,1024]
    const float* out_w = (const float*)d_in[2];   // [1024,1024]
    const float* qp    = (const float*)d_in[3];   // [64]
    float* out = (float*)d_out;                   // [2,2048,1024] fp32

    const long NELEM = (long)2 * S_LEN * EMB;     // 4,194,304
    __hip_bfloat16* Q   = (__hip_bfloat16*)d_ws;  // [B,H,S,D] (x0.125)
    __hip_bfloat16* K   = Q + NELEM;              // [B,H,S,D]
    __hip_bfloat16* Vt  = K + NELEM;              // [B,H,D,S]
    __hip_bfloat16* O   = Vt + NELEM;             // [B,S,E]
    __hip_bfloat16* xb  = O + NELEM;              // [4096][1024]
    __hip_bfloat16* wqb = xb + NELEM;             // [3072][1024]
    __hip_bfloat16* wob = wqb + (long)3072 * 1024;// [1024][1024]

    dim3 blk(256);
    cvt_f32_bf16<<<dim3(2048), blk, 0, stream>>>(x, xb, (long)4096 * 1024);
    cvt_f32_bf16<<<dim3(1536), blk, 0, stream>>>(qkv_w, wqb, (long)3072 * 1024);
    cvt_f32_bf16<<<dim3(512),  blk, 0, stream>>>(out_w, wob, (long)1024 * 1024);

    gemm_mfma<0><<<dim3(3072 / 128, 4096 / 128), blk, 0, stream>>>(
        xb, wqb, qp, Q, K, Vt, nullptr);
    attn_mfma<<<dim3(S_LEN / 64, 32), blk, 0, stream>>>(Q, K, Vt, O);
    gemm_mfma<1><<<dim3(1024 / 128, 4096 / 128), blk, 0, stream>>>(
        O, wob, nullptr, nullptr, nullptr, nullptr, out);
}

// Round 4
// 155.657 us; speedup vs baseline: 16.9950x; 1.2711x over previous
//
#include <hip/hip_runtime.h>
#include <hip/hip_bf16.h>

#define S_LEN 2048
#define EMB 1024
#define NH 16
#define HD 64
// M = B*S = 4096 rows

typedef __attribute__((ext_vector_type(8))) __bf16 bf16x8;
typedef __attribute__((ext_vector_type(4))) float f32x4;

__device__ inline void gload_lds16(const void* g, void* l) {
    __builtin_amdgcn_global_load_lds(
        (const __attribute__((address_space(1))) unsigned int*)g,
        (__attribute__((address_space(3))) unsigned int*)l, 16, 0, 0);
}

// ---------------------------------------------------------------------------
// Kernel 0: fp32 -> bf16 conversion of x, qkv_w, out_w in ONE launch.
// ---------------------------------------------------------------------------
__global__ __launch_bounds__(256) void cvt_all(
    const float* __restrict__ x, const float* __restrict__ wq,
    const float* __restrict__ wo,
    __hip_bfloat16* __restrict__ xb, __hip_bfloat16* __restrict__ wqb,
    __hip_bfloat16* __restrict__ wob)
{
    const long C_X = (long)4096 * 1024 / 4;       // 1,048,576
    const long C_WQ = (long)3072 * 1024 / 4;      // 786,432
    long c = (long)blockIdx.x * 256 + threadIdx.x;
    const float* in;
    __hip_bfloat16* out;
    if (c < C_X) { in = x; out = xb; }
    else if (c < C_X + C_WQ) { in = wq; out = wqb; c -= C_X; }
    else { in = wo; out = wob; c -= C_X + C_WQ; }
    long i = c * 4;
    float4 v = *(const float4*)(in + i);
    __hip_bfloat16 b0 = __float2bfloat16(v.x);
    __hip_bfloat16 b1 = __float2bfloat16(v.y);
    __hip_bfloat16 b2 = __float2bfloat16(v.z);
    __hip_bfloat16 b3 = __float2bfloat16(v.w);
    ushort4 o = {*(unsigned short*)&b0, *(unsigned short*)&b1,
                 *(unsigned short*)&b2, *(unsigned short*)&b3};
    *(ushort4*)(out + i) = o;
}

// ---------------------------------------------------------------------------
// MFMA GEMM core (m97 structure): C = A @ B^T, 128x128 tile, BK=64, 4 waves.
// EPI=0: quantum epilogue (cos*cos, scatter Q/K/Vt).  EPI=1: fp32 C store.
// ---------------------------------------------------------------------------
template <int EPI>
__global__ __launch_bounds__(256) void gemm_mfma(
    const __hip_bfloat16* __restrict__ A,   // [M][1024]
    const __hip_bfloat16* __restrict__ B,   // [N][1024]
    const float* __restrict__ qp,           // [64] (EPI=0)
    __hip_bfloat16* __restrict__ Q,         // EPI=0 outputs
    __hip_bfloat16* __restrict__ Kp,
    __hip_bfloat16* __restrict__ Vt,
    float* __restrict__ C)                  // EPI=1 output
{
    const int Kd = 1024;
    __shared__ __align__(16) char Ash[128 * 128];
    __shared__ __align__(16) char Bsh[128 * 128];

    const int t  = threadIdx.x;
    const int w  = t >> 6;
    const int l  = t & 63;
    const int lg = l >> 4, lm = l & 15;
    const int wr = w >> 1, wc = w & 1;
    const int m0 = blockIdx.y * 128;
    const int n0 = blockIdx.x * 128;

    const int r8 = l >> 3;
    const int sb = ((l & 7) * 16) ^ (r8 << 4);
    const char* srcA = (const char*)A + ((long)(m0 + w * 32 + r8) * Kd) * 2 + sb;
    const char* srcB = (const char*)B + ((long)(n0 + w * 32 + r8) * Kd) * 2 + sb;

    f32x4 acc[4][4];
#pragma unroll
    for (int i = 0; i < 4; i++)
#pragma unroll
        for (int j = 0; j < 4; j++) acc[i][j] = (f32x4){0.f, 0.f, 0.f, 0.f};

    for (int kt = 0; kt < Kd * 2; kt += 128) {
#pragma unroll
        for (int j = 0; j < 4; j++) {
            gload_lds16(srcA + (long)j * 8 * Kd * 2 + kt, Ash + (w * 32 + j * 8) * 128);
            gload_lds16(srcB + (long)j * 8 * Kd * 2 + kt, Bsh + (w * 32 + j * 8) * 128);
        }
        __syncthreads();
#pragma unroll
        for (int kk = 0; kk < 2; kk++) {
            bf16x8 af[4], bfr[4];
            const int sw = (lm & 7) << 4;
            const int co = (kk * 64 + lg * 16);
#pragma unroll
            for (int mi = 0; mi < 4; mi++)
                af[mi] = *(const bf16x8*)(Ash + (wr * 64 + mi * 16 + lm) * 128 + (co ^ sw));
#pragma unroll
            for (int ni = 0; ni < 4; ni++)
                bfr[ni] = *(const bf16x8*)(Bsh + (wc * 64 + ni * 16 + lm) * 128 + (co ^ sw));
#pragma unroll
            for (int mi = 0; mi < 4; mi++)
#pragma unroll
                for (int ni = 0; ni < 4; ni++)
                    acc[mi][ni] = __builtin_amdgcn_mfma_f32_16x16x32_bf16(
                        af[mi], bfr[ni], acc[mi][ni], 0, 0, 0);
        }
        __syncthreads();
    }

    if constexpr (EPI == 0) {
        const int which = n0 >> 10;
        float cqp[4];
#pragma unroll
        for (int ni = 0; ni < 4; ni++)
            cqp[ni] = __cosf(qp[(wc * 64 + ni * 16 + lm) & 63]);
#pragma unroll
        for (int mi = 0; mi < 4; mi++) {
#pragma unroll
            for (int r = 0; r < 4; r++) {
                int m = m0 + wr * 64 + mi * 16 + lg * 4 + r;
                int b = m >> 11, s = m & 2047;
#pragma unroll
                for (int ni = 0; ni < 4; ni++) {
                    int n = n0 + wc * 64 + ni * 16 + lm;
                    int d = n & 63;
                    int h = (n & 1023) >> 6;
                    int bh = b * NH + h;
                    float val = __cosf(acc[mi][ni][r]) * cqp[ni];
                    if (which == 0)
                        Q[((long)bh * S_LEN + s) * HD + d] = __float2bfloat16(val * 0.125f);
                    else if (which == 1)
                        Kp[((long)bh * S_LEN + s) * HD + d] = __float2bfloat16(val);
                    else
                        Vt[((long)bh * HD + d) * S_LEN + s] = __float2bfloat16(val);
                }
            }
        }
    } else {
#pragma unroll
        for (int mi = 0; mi < 4; mi++)
#pragma unroll
            for (int r = 0; r < 4; r++) {
                int m = m0 + wr * 64 + mi * 16 + lg * 4 + r;
#pragma unroll
                for (int ni = 0; ni < 4; ni++) {
                    int n = n0 + wc * 64 + ni * 16 + lm;
                    C[(long)m * 1024 + n] = acc[mi][ni][r];
                }
            }
    }
}

// ---------------------------------------------------------------------------
// Kernel 2: MFMA flash attention, FIXED-MAX softmax (|S| <= 8 provably:
// |q*0.125| <= 0.125, |k| <= 1, D=64). P = exp(S-8); no max tracking, no
// O rescale, no in-loop shuffles. K/V staged via global_load_lds DMA with
// pre-swizzled SOURCE + linear LDS dest + swizzled READ (rule #21).
// ---------------------------------------------------------------------------
__global__ __launch_bounds__(256) void attn_mfma(
    const __hip_bfloat16* __restrict__ Q,
    const __hip_bfloat16* __restrict__ K,
    const __hip_bfloat16* __restrict__ Vt,  // [B,H,D,S]
    __hip_bfloat16* __restrict__ O)
{
    __shared__ __align__(16) char Ksh[64 * 128];
    __shared__ __align__(16) char Vsh[64 * 128];
    __shared__ __align__(16) char Psh[4 * 16 * 128];

    const int bh = blockIdx.y;
    const int b  = bh >> 4, h = bh & 15;
    const int q0 = blockIdx.x * 64;
    const int t  = threadIdx.x;
    const int w  = t >> 6;
    const int l  = t & 63;
    const int lg = l >> 4;
    const int lm = l & 15;

    const __hip_bfloat16* Qr =
        Q + ((long)bh * S_LEN + q0 + w * 16 + lm) * HD + lg * 8;
    const bf16x8 qa0 = *(const bf16x8*)(Qr);
    const bf16x8 qa1 = *(const bf16x8*)(Qr + 32);

    f32x4 oacc[4];
#pragma unroll
    for (int n = 0; n < 4; n++) oacc[n] = (f32x4){0.f, 0.f, 0.f, 0.f};
    float lsum[4] = {0.f, 0.f, 0.f, 0.f};

    char* Pw = Psh + w * 2048;
    const char* Kgb = (const char*)(K + (long)bh * S_LEN * HD);
    const char* Vgb = (const char*)(Vt + (long)bh * HD * S_LEN);

    // lane l covers LDS row rr = w*8 + (l>>3) (+32 on chunk 2), 16B col (l&7).
    // Linear LDS dest (base + l*16); source byte pre-swizzled by ((rr&7)<<4).
    const int swb = ((l & 7) * 16) ^ (((l >> 3) & 7) << 4);
    const int row0 = w * 8 + (l >> 3);
    const char* Ksrc = Kgb + (long)row0 * 128 + swb;                  // +kt*128
    const char* Vsrc0 = Vgb + (long)row0 * (S_LEN * 2) + swb;         // +kt*2
    const char* Vsrc1 = Vgb + (long)(row0 + 32) * (S_LEN * 2) + swb;  // +kt*2

    for (int kt = 0; kt < S_LEN; kt += 64) {
        __syncthreads();  // previous tile's LDS reads done
        gload_lds16(Ksrc + (long)kt * 128, Ksh + w * 1024);
        gload_lds16(Ksrc + (long)(kt + 32) * 128, Ksh + w * 1024 + 4096);
        gload_lds16(Vsrc0 + (long)kt * 2, Vsh + w * 1024);
        gload_lds16(Vsrc1 + (long)kt * 2, Vsh + w * 1024 + 4096);
        __syncthreads();  // DMA drained (vmcnt before barrier) + all staged

        f32x4 sacc[4];
#pragma unroll
        for (int n0 = 0; n0 < 4; n0++) {
            f32x4 s = (f32x4){0.f, 0.f, 0.f, 0.f};
            int row = n0 * 16 + lm;
            int swr = (row & 7) << 4;
            bf16x8 b0 = *(const bf16x8*)(Ksh + row * 128 + ((lg * 16) ^ swr));
            bf16x8 b1 = *(const bf16x8*)(Ksh + row * 128 + ((64 + lg * 16) ^ swr));
            s = __builtin_amdgcn_mfma_f32_16x16x32_bf16(qa0, b0, s, 0, 0, 0);
            s = __builtin_amdgcn_mfma_f32_16x16x32_bf16(qa1, b1, s, 0, 0, 0);
            sacc[n0] = s;
        }

        // fixed-max softmax: P = exp(S - 8), lane-local row-sum accumulation
#pragma unroll
        for (int r = 0; r < 4; r++) {
            int q = lg * 4 + r;
            int swp = (q & 7) << 4;
            float ls = 0.f;
#pragma unroll
            for (int n0 = 0; n0 < 4; n0++) {
                float p = __expf(sacc[n0][r] - 8.0f);
                ls += p;
                int key = n0 * 16 + lm;
                *(__hip_bfloat16*)(Pw + q * 128 + ((key * 2) ^ swp)) =
                    __float2bfloat16(p);
            }
            lsum[r] += ls;
        }

#pragma unroll
        for (int kk = 0; kk < 2; kk++) {
            bf16x8 pa = *(const bf16x8*)(
                Pw + lm * 128 + ((kk * 64 + lg * 16) ^ ((lm & 7) << 4)));
#pragma unroll
            for (int n0 = 0; n0 < 4; n0++) {
                int row = n0 * 16 + lm;
                bf16x8 vb = *(const bf16x8*)(
                    Vsh + row * 128 + ((kk * 64 + lg * 16) ^ ((row & 7) << 4)));
                oacc[n0] =
                    __builtin_amdgcn_mfma_f32_16x16x32_bf16(pa, vb, oacc[n0], 0, 0, 0);
            }
        }
    }

    // final: cross-lane row-sum reduce (16-lane groups), normalize, store
#pragma unroll
    for (int r = 0; r < 4; r++) {
        float ls = lsum[r];
        ls += __shfl_xor(ls, 1, 64);
        ls += __shfl_xor(ls, 2, 64);
        ls += __shfl_xor(ls, 4, 64);
        ls += __shfl_xor(ls, 8, 64);
        float inv = 1.f / ls;
        int qrow = q0 + w * 16 + lg * 4 + r;
        long base = ((long)b * S_LEN + qrow) * EMB + h * HD;
#pragma unroll
        for (int n0 = 0; n0 < 4; n0++)
            O[base + n0 * 16 + lm] = __float2bfloat16(oacc[n0][r] * inv);
    }
}

extern "C" void kernel_launch(void* const* d_in, const int* in_sizes, int n_in,
                              void* d_out, int out_size, void* d_ws, size_t ws_size,
                              hipStream_t stream) {
    const float* x     = (const float*)d_in[0];   // [2,2048,1024]
    const float* qkv_w = (const float*)d_in[1];   // [3072,1024]
    const float* out_w = (const float*)d_in[2];   // [1024,1024]
    const float* qp    = (const float*)d_in[3];   // [64]
    float* out = (float*)d_out;                   // [2,2048,1024] fp32

    const long NELEM = (long)2 * S_LEN * EMB;     // 4,194,304
    __hip_bfloat16* Q   = (__hip_bfloat16*)d_ws;  // [B,H,S,D] (x0.125)
    __hip_bfloat16* K   = Q + NELEM;              // [B,H,S,D]
    __hip_bfloat16* Vt  = K + NELEM;              // [B,H,D,S]
    __hip_bfloat16* O   = Vt + NELEM;             // [B,S,E]
    __hip_bfloat16* xb  = O + NELEM;              // [4096][1024]
    __hip_bfloat16* wqb = xb + NELEM;             // [3072][1024]
    __hip_bfloat16* wob = wqb + (long)3072 * 1024;// [1024][1024]

    dim3 blk(256);
    cvt_all<<<dim3(8192), blk, 0, stream>>>(x, qkv_w, out_w, xb, wqb, wob);
    gemm_mfma<0><<<dim3(3072 / 128, 4096 / 128), blk, 0, stream>>>(
        xb, wqb, qp, Q, K, Vt, nullptr);
    attn_mfma<<<dim3(S_LEN / 64, 32), blk, 0, stream>>>(Q, K, Vt, O);
    gemm_mfma<1><<<dim3(1024 / 128, 4096 / 128), blk, 0, stream>>>(
        O, wob, nullptr, nullptr, nullptr, nullptr, out);
}